// Round 2
// baseline (830.296 us; speedup 1.0000x reference)
//
#include <hip/hip_runtime.h>
#include <hip/hip_bf16.h>
#include <stdint.h>
#include <stddef.h>

#define DI __device__ __forceinline__

typedef __attribute__((ext_vector_type(8))) short short8;
typedef __attribute__((ext_vector_type(4))) float f32x4;
typedef __attribute__((ext_vector_type(4))) unsigned short ushort4_t;
typedef __attribute__((ext_vector_type(8))) unsigned short ushort8_t;

constexpr int E = 2048;
constexpr int TOK = 4096;   // B*S
constexpr int S = 2048;

// RNE float->bf16 (finite values only; matches jnp/HW round-to-nearest-even)
DI unsigned short f2bf(float f) {
  unsigned u = __builtin_bit_cast(unsigned, f);
  unsigned r = (u + 0x7FFFu + ((u >> 16) & 1u)) >> 16;
  return (unsigned short)r;
}
DI float bf2f(unsigned short h) {
  unsigned u = ((unsigned)h) << 16;
  return __builtin_bit_cast(float, u);
}

#define GLDS16(gp, lp) __builtin_amdgcn_global_load_lds( \
    (const __attribute__((address_space(1))) void*)(gp), \
    (__attribute__((address_space(3))) void*)(lp), 16, 0, 0)

// ---------------- weight absmean sum ----------------
__global__ __launch_bounds__(256) void wabs_kernel(const float* w0, const float* w1,
                                                   const float* w2, const float* w3,
                                                   double* wsum) {
  int t = blockIdx.y;
  const float* w = t == 0 ? w0 : t == 1 ? w1 : t == 2 ? w2 : w3;
  int tid = threadIdx.x;
  const float4* w4 = (const float4*)w;
  int base = blockIdx.x * 256 + tid;          // 64 blocks -> 16384 threads
  float s = 0.f;
  for (int i = 0; i < 64; ++i) {              // 16384*64 = 1M float4 = 4M floats
    float4 v = w4[base + i * 16384];
    s += fabsf(v.x) + fabsf(v.y) + fabsf(v.z) + fabsf(v.w);
  }
  s += __shfl_xor(s, 32); s += __shfl_xor(s, 16); s += __shfl_xor(s, 8);
  s += __shfl_xor(s, 4);  s += __shfl_xor(s, 2);  s += __shfl_xor(s, 1);
  __shared__ float red[4];
  int lane = tid & 63, wid = tid >> 6;
  if (lane == 0) red[wid] = s;
  __syncthreads();
  if (tid == 0) {
    double tot = (double)red[0] + (double)red[1] + (double)red[2] + (double)red[3];
    atomicAdd(&wsum[t], tot);
  }
}

// ---------------- weight ternary quant ----------------
__global__ __launch_bounds__(256) void wquant_kernel(const float* w0, const float* w1,
                                                     const float* w2, const float* w3,
                                                     unsigned short* wq, const double* wsum) {
  int t = blockIdx.y;
  const float* w = t == 0 ? w0 : t == 1 ? w1 : t == 2 ? w2 : w3;
  unsigned short* o = wq + (size_t)t * E * E;
  float mean = (float)(wsum[t] * (1.0 / 4194304.0));
  float wsc = fmaxf(mean, 1e-5f);
  float sw = 1.0f / wsc;
  int idx = (blockIdx.x * 256 + threadIdx.x) * 8;
  float4 a = *(const float4*)(w + idx);
  float4 b = *(const float4*)(w + idx + 4);
  float v[8] = {a.x, a.y, a.z, a.w, b.x, b.y, b.z, b.w};
  ushort8_t r;
#pragma unroll
  for (int j = 0; j < 8; ++j) {
    float q = rintf(v[j] * sw);
    q = fminf(fmaxf(q, -1.f), 1.f);
    r[j] = f2bf(q);                           // {-1,0,1} exact in bf16
  }
  *(ushort8_t*)(o + idx) = r;
}

// ---------------- per-token int8 activation quant ----------------
__global__ __launch_bounds__(256) void actquant_kernel(const float* in, unsigned short* outq,
                                                       float* tokscale) {
  int tok = blockIdx.x;
  int tid = threadIdx.x;
  const float* row = in + (size_t)tok * E;
  float4 a = *(const float4*)(row + tid * 8);
  float4 b = *(const float4*)(row + tid * 8 + 4);
  float v[8] = {a.x, a.y, a.z, a.w, b.x, b.y, b.z, b.w};
  float am = 0.f;
#pragma unroll
  for (int j = 0; j < 8; ++j) am = fmaxf(am, fabsf(v[j]));
  am = fmaxf(am, __shfl_xor(am, 32)); am = fmaxf(am, __shfl_xor(am, 16));
  am = fmaxf(am, __shfl_xor(am, 8));  am = fmaxf(am, __shfl_xor(am, 4));
  am = fmaxf(am, __shfl_xor(am, 2));  am = fmaxf(am, __shfl_xor(am, 1));
  __shared__ float red[4];
  int lane = tid & 63, wid = tid >> 6;
  if (lane == 0) red[wid] = am;
  __syncthreads();
  am = fmaxf(fmaxf(red[0], red[1]), fmaxf(red[2], red[3]));
  float a_ = fmaxf(am, 1e-5f);
  float sx = 127.0f / a_;
  ushort8_t r;
#pragma unroll
  for (int j = 0; j < 8; ++j) {
    float q = rintf(v[j] * sx);
    q = fminf(fmaxf(q, -128.f), 127.f);
    r[j] = f2bf(q);                           // ints in [-128,127] exact in bf16
  }
  *(ushort8_t*)(outq + (size_t)tok * E + tid * 8) = r;
  if (tid == 0) tokscale[tok] = a_ / 127.0f;
}

// ---------------- bf16 exact-int GEMM: C[M][N] = (A[M][K] . B[N][K]^T) * ts[row] * wscale
// transposed=1: write to vT layout [b(2)][col(2048)][s(2048)] (for attention V)
__global__ __launch_bounds__(256) void gemm_bt_kernel(const unsigned short* A, const unsigned short* B,
                                                      float* C, const float* tokscale,
                                                      const double* wsum, int transposed) {
  __shared__ unsigned short As[128 * 64];
  __shared__ unsigned short Bs[128 * 64];
  int tid = threadIdx.x;
  int lane = tid & 63, wid = tid >> 6;
  int bm = blockIdx.x >> 4, bn = blockIdx.x & 15;   // 32 x 16 tiles of 128x128
  int wr = wid >> 1, wc = wid & 1;
  f32x4 acc[4][4];
#pragma unroll
  for (int i = 0; i < 4; ++i)
#pragma unroll
    for (int j = 0; j < 4; ++j) acc[i][j] = (f32x4){0.f, 0.f, 0.f, 0.f};

  for (int k0 = 0; k0 < E; k0 += 64) {
#pragma unroll
    for (int i = 0; i < 4; ++i) {
      int c = i * 256 + tid;                        // 1024 16B-chunks per tile
      int row = c >> 3, col = (c & 7) * 8;
      GLDS16(A + (size_t)(bm * 128 + row) * E + k0 + col, &As[(i * 256 + wid * 64) * 8]);
      GLDS16(B + (size_t)(bn * 128 + row) * E + k0 + col, &Bs[(i * 256 + wid * 64) * 8]);
    }
    __syncthreads();
#pragma unroll
    for (int kc = 0; kc < 2; ++kc) {
      short8 af[4], bf_[4];
#pragma unroll
      for (int mi = 0; mi < 4; ++mi)
        af[mi] = *(const short8*)&As[(wr * 64 + mi * 16 + (lane & 15)) * 64 + kc * 32 + (lane >> 4) * 8];
#pragma unroll
      for (int nj = 0; nj < 4; ++nj)
        bf_[nj] = *(const short8*)&Bs[(wc * 64 + nj * 16 + (lane & 15)) * 64 + kc * 32 + (lane >> 4) * 8];
#pragma unroll
      for (int mi = 0; mi < 4; ++mi)
#pragma unroll
        for (int nj = 0; nj < 4; ++nj)
          acc[mi][nj] = __builtin_amdgcn_mfma_f32_16x16x32_bf16(af[mi], bf_[nj], acc[mi][nj], 0, 0, 0);
    }
    __syncthreads();
  }

  float wsc = fmaxf((float)(wsum[0] * (1.0 / 4194304.0)), 1e-5f);
  int rbase = bm * 128 + wr * 64 + (lane >> 4) * 4;
  int cbase = bn * 128 + wc * 64 + (lane & 15);
  if (!transposed) {
#pragma unroll
    for (int mi = 0; mi < 4; ++mi)
#pragma unroll
      for (int nj = 0; nj < 4; ++nj) {
        int row0 = rbase + mi * 16;
        int col = cbase + nj * 16;
#pragma unroll
        for (int r = 0; r < 4; ++r) {
          int row = row0 + r;
          C[(size_t)row * E + col] = acc[mi][nj][r] * tokscale[row] * wsc;
        }
      }
  } else {
#pragma unroll
    for (int mi = 0; mi < 4; ++mi)
#pragma unroll
      for (int nj = 0; nj < 4; ++nj) {
        int row0 = rbase + mi * 16;
        int col = cbase + nj * 16;
        f32x4 v;
#pragma unroll
        for (int r = 0; r < 4; ++r) v[r] = acc[mi][nj][r] * tokscale[row0 + r] * wsc;
        size_t off = ((size_t)((row0 >> 11) * 2048 + col)) * S + (row0 & 2047);
        *(f32x4*)(C + off) = v;                     // 4 consecutive s positions
      }
  }
}

// ---------------- flash attention, hi/lo-split bf16 MFMA ----------------
// q,k: [4096][2048] f32 ; vT: [b][h*128+d][s] f32 ; ao: [4096][2048] f32
__global__ __launch_bounds__(256) void attn_kernel(const float* q, const float* k,
                                                   const float* vT, float* ao) {
  constexpr int KB = 32;
  __shared__ unsigned short Khi[KB * 128], Klo[KB * 128];   // [kv][D]
  __shared__ unsigned short Vhi[128 * KB], Vlo[128 * KB];   // [d][kv]
  __shared__ float Pl[4][16 * KB];                          // per-wave P [q][kv]
  int tid = threadIdx.x, lane = tid & 63, wid = tid >> 6;
  int qb = blockIdx.x, bh = blockIdx.y;
  int b = bh >> 4, h = bh & 15;
  int qs = qb * 64;
  int g = lane >> 4, li = lane & 15;
  const float invs = 0.088388347648318447f;  // fp32(1/sqrt(128))

  // Q fragments (A-operand), pre-scaled, split hi/lo
  short8 qh[4], ql[4];
  {
    int qtok = b * S + qs + wid * 16 + li;
    const float* qp = q + (size_t)qtok * E + h * 128;
#pragma unroll
    for (int kc = 0; kc < 4; ++kc) {
      int kb = kc * 32 + g * 8;
      float4 a = *(const float4*)(qp + kb);
      float4 c = *(const float4*)(qp + kb + 4);
      float v[8] = {a.x, a.y, a.z, a.w, c.x, c.y, c.z, c.w};
#pragma unroll
      for (int j = 0; j < 8; ++j) {
        float sv = v[j] * invs;
        unsigned short hb = f2bf(sv);
        qh[kc][j] = (short)hb;
        ql[kc][j] = (short)f2bf(sv - bf2f(hb));
      }
    }
  }

  f32x4 o[8];
#pragma unroll
  for (int i = 0; i < 8; ++i) o[i] = (f32x4){0.f, 0.f, 0.f, 0.f};
  float m_[4], l_[4];
#pragma unroll
  for (int r = 0; r < 4; ++r) { m_[r] = -__builtin_inff(); l_[r] = 0.f; }

  int ntiles = (qs + 64) / KB;   // 2*qb + 2
  for (int kt = 0; kt < ntiles; ++kt) {
    // ---- stage K and V^T tiles (fp32 -> hi/lo bf16, XOR-swizzled) ----
#pragma unroll
    for (int it = 0; it < 4; ++it) {
      int chunk = it * 256 + tid;
      {
        int r = chunk >> 5, c = (chunk & 31) * 4;
        float4 v = *(const float4*)(k + (size_t)(b * S + kt * KB + r) * E + h * 128 + c);
        float vv[4] = {v.x, v.y, v.z, v.w};
        ushort4_t hh, ll;
#pragma unroll
        for (int j = 0; j < 4; ++j) { hh[j] = f2bf(vv[j]); ll[j] = f2bf(vv[j] - bf2f(hh[j])); }
        int byte = r * 256 + c * 2; byte ^= (r & 7) << 4;
        *(ushort4_t*)((char*)Khi + byte) = hh;
        *(ushort4_t*)((char*)Klo + byte) = ll;
      }
      {
        int d = chunk >> 3, c = (chunk & 7) * 4;
        float4 v = *(const float4*)(vT + (size_t)(b * 2048 + h * 128 + d) * S + kt * KB + c);
        float vv[4] = {v.x, v.y, v.z, v.w};
        ushort4_t hh, ll;
#pragma unroll
        for (int j = 0; j < 4; ++j) { hh[j] = f2bf(vv[j]); ll[j] = f2bf(vv[j] - bf2f(hh[j])); }
        int byte = d * 64 + c * 2; byte ^= (d & 7) << 4;
        *(ushort4_t*)((char*)Vhi + byte) = hh;
        *(ushort4_t*)((char*)Vlo + byte) = ll;
      }
    }
    __syncthreads();

    // ---- QK^T (hi*hi + hi*lo + lo*hi) ----
    f32x4 s[2];
    s[0] = (f32x4){0.f, 0.f, 0.f, 0.f};
    s[1] = (f32x4){0.f, 0.f, 0.f, 0.f};
#pragma unroll
    for (int st = 0; st < 2; ++st) {
#pragma unroll
      for (int kc = 0; kc < 4; ++kc) {
        int kv = st * 16 + li;
        int byte = kv * 256 + (kc * 32 + g * 8) * 2; byte ^= (kv & 7) << 4;
        short8 kh = *(const short8*)((char*)Khi + byte);
        short8 kl = *(const short8*)((char*)Klo + byte);
        s[st] = __builtin_amdgcn_mfma_f32_16x16x32_bf16(qh[kc], kh, s[st], 0, 0, 0);
        s[st] = __builtin_amdgcn_mfma_f32_16x16x32_bf16(qh[kc], kl, s[st], 0, 0, 0);
        s[st] = __builtin_amdgcn_mfma_f32_16x16x32_bf16(ql[kc], kh, s[st], 0, 0, 0);
      }
    }
    // causal mask (only tiles reaching past the block's first row)
    if (kt * KB + KB - 1 > qs) {
#pragma unroll
      for (int st = 0; st < 2; ++st)
#pragma unroll
        for (int r = 0; r < 4; ++r) {
          int kvg = kt * KB + st * 16 + li;
          int qg = qs + wid * 16 + g * 4 + r;
          if (kvg > qg) s[st][r] = -1e30f;
        }
    }
    // ---- online softmax ----
    float mnew[4], alpha[4];
#pragma unroll
    for (int r = 0; r < 4; ++r) {
      float mloc = fmaxf(s[0][r], s[1][r]);
      mloc = fmaxf(mloc, __shfl_xor(mloc, 1));
      mloc = fmaxf(mloc, __shfl_xor(mloc, 2));
      mloc = fmaxf(mloc, __shfl_xor(mloc, 4));
      mloc = fmaxf(mloc, __shfl_xor(mloc, 8));
      mnew[r] = fmaxf(m_[r], mloc);
      alpha[r] = expf(m_[r] - mnew[r]);
      m_[r] = mnew[r];
    }
#pragma unroll
    for (int st = 0; st < 2; ++st)
#pragma unroll
      for (int r = 0; r < 4; ++r) s[st][r] = expf(s[st][r] - mnew[r]);
#pragma unroll
    for (int r = 0; r < 4; ++r) {
      float ps = s[0][r] + s[1][r];
      ps += __shfl_xor(ps, 1); ps += __shfl_xor(ps, 2);
      ps += __shfl_xor(ps, 4); ps += __shfl_xor(ps, 8);
      l_[r] = l_[r] * alpha[r] + ps;
    }
    // write P to per-wave LDS (swizzled)
#pragma unroll
    for (int st = 0; st < 2; ++st)
#pragma unroll
      for (int r = 0; r < 4; ++r) {
        int qrow = g * 4 + r, kv = st * 16 + li;
        int byte = qrow * 128 + kv * 4; byte ^= (qrow & 7) << 4;
        *(float*)((char*)&Pl[wid][0] + byte) = s[st][r];
      }
    // rescale o
#pragma unroll
    for (int db = 0; db < 8; ++db)
#pragma unroll
      for (int r = 0; r < 4; ++r) o[db][r] *= alpha[r];
    // ---- PV (hi/lo split) ----
    {
      int b0 = li * 128 + g * 32; int swz = (li & 7) << 4;
      float4 p0 = *(const float4*)((char*)&Pl[wid][0] + (b0 ^ swz));
      float4 p1 = *(const float4*)((char*)&Pl[wid][0] + ((b0 + 16) ^ swz));
      float pv[8] = {p0.x, p0.y, p0.z, p0.w, p1.x, p1.y, p1.z, p1.w};
      short8 pah, pal;
#pragma unroll
      for (int j = 0; j < 8; ++j) {
        unsigned short hb = f2bf(pv[j]);
        pah[j] = (short)hb;
        pal[j] = (short)f2bf(pv[j] - bf2f(hb));
      }
#pragma unroll
      for (int db = 0; db < 8; ++db) {
        int d = db * 16 + li;
        int byte = d * 64 + g * 16; byte ^= (d & 7) << 4;
        short8 vh = *(const short8*)((char*)Vhi + byte);
        short8 vl = *(const short8*)((char*)Vlo + byte);
        o[db] = __builtin_amdgcn_mfma_f32_16x16x32_bf16(pah, vh, o[db], 0, 0, 0);
        o[db] = __builtin_amdgcn_mfma_f32_16x16x32_bf16(pah, vl, o[db], 0, 0, 0);
        o[db] = __builtin_amdgcn_mfma_f32_16x16x32_bf16(pal, vh, o[db], 0, 0, 0);
      }
    }
    __syncthreads();
  }
  // epilogue: normalize and store
#pragma unroll
  for (int r = 0; r < 4; ++r) l_[r] = 1.0f / l_[r];
  int qtokr = b * S + qs + wid * 16 + g * 4;
#pragma unroll
  for (int db = 0; db < 8; ++db)
#pragma unroll
    for (int r = 0; r < 4; ++r)
      ao[(size_t)(qtokr + r) * E + h * 128 + db * 16 + li] = o[db][r] * l_[r];
}

// ---------------- launch ----------------
extern "C" void kernel_launch(void* const* d_in, const int* in_sizes, int n_in,
                              void* d_out, int out_size, void* d_ws, size_t ws_size,
                              hipStream_t stream) {
  (void)in_sizes; (void)n_in; (void)out_size; (void)ws_size;
  const float* x  = (const float*)d_in[0];
  const float* w0 = (const float*)d_in[1];
  const float* w1 = (const float*)d_in[2];
  const float* w2 = (const float*)d_in[3];
  const float* w3 = (const float*)d_in[4];
  float* out = (float*)d_out;
  char* ws = (char*)d_ws;

  double* wsum = (double*)ws;                         // 32 B
  float* tsx   = (float*)(ws + 256);                  // 16 KB
  float* tsa   = (float*)(ws + 256 + 16384);          // 16 KB
  unsigned short* wq = (unsigned short*)(ws + 33024); // 4 x 8.39 MB
  size_t WQB = (size_t)E * E;
  unsigned short* xq = wq + 4 * WQB;                  // 16.78 MB
  float* qb_ = (float*)(xq + (size_t)TOK * E);        // 33.55 MB each
  float* kb_ = qb_ + (size_t)TOK * E;
  float* vT  = kb_ + (size_t)TOK * E;
  float* aof = vT  + (size_t)TOK * E;
  unsigned short* aq = xq;                            // alias: xq dead after v-GEMM

  hipMemsetAsync(ws, 0, 64, stream);
  wabs_kernel<<<dim3(64, 4), 256, 0, stream>>>(w0, w1, w2, w3, wsum);
  wquant_kernel<<<dim3(2048, 4), 256, 0, stream>>>(w0, w1, w2, w3, wq, wsum);
  actquant_kernel<<<TOK, 256, 0, stream>>>(x, xq, tsx);
  gemm_bt_kernel<<<512, 256, 0, stream>>>(xq, wq + 0 * WQB, qb_, tsx, wsum + 0, 0);
  gemm_bt_kernel<<<512, 256, 0, stream>>>(xq, wq + 1 * WQB, kb_, tsx, wsum + 1, 0);
  gemm_bt_kernel<<<512, 256, 0, stream>>>(xq, wq + 2 * WQB, vT,  tsx, wsum + 2, 1);
  attn_kernel<<<dim3(32, 32), 256, 0, stream>>>(qb_, kb_, vT, aof);
  actquant_kernel<<<TOK, 256, 0, stream>>>(aof, aq, tsa);
  gemm_bt_kernel<<<512, 256, 0, stream>>>(aq, wq + 3 * WQB, out, tsa, wsum + 3, 0);
}

// Round 3
// 807.273 us; speedup vs baseline: 1.0285x; 1.0285x over previous
//
#include <hip/hip_runtime.h>
#include <hip/hip_bf16.h>
#include <stdint.h>
#include <stddef.h>

#define DI __device__ __forceinline__

typedef __attribute__((ext_vector_type(8))) short short8;
typedef __attribute__((ext_vector_type(4))) float f32x4;
typedef __attribute__((ext_vector_type(4))) unsigned short ushort4_t;
typedef __attribute__((ext_vector_type(8))) unsigned short ushort8_t;

constexpr int E = 2048;
constexpr int TOK = 4096;   // B*S
constexpr int S = 2048;

// RNE float->bf16 (finite values only; matches jnp/HW round-to-nearest-even)
DI unsigned short f2bf(float f) {
  unsigned u = __builtin_bit_cast(unsigned, f);
  unsigned r = (u + 0x7FFFu + ((u >> 16) & 1u)) >> 16;
  return (unsigned short)r;
}
DI float bf2f(unsigned short h) {
  unsigned u = ((unsigned)h) << 16;
  return __builtin_bit_cast(float, u);
}

#define GLDS16(gp, lp) __builtin_amdgcn_global_load_lds( \
    (const __attribute__((address_space(1))) void*)(gp), \
    (__attribute__((address_space(3))) void*)(lp), 16, 0, 0)

// ---------------- weight absmean sum ----------------
__global__ __launch_bounds__(256) void wabs_kernel(const float* w0, const float* w1,
                                                   const float* w2, const float* w3,
                                                   double* wsum) {
  int t = blockIdx.y;
  const float* w = t == 0 ? w0 : t == 1 ? w1 : t == 2 ? w2 : w3;
  int tid = threadIdx.x;
  const float4* w4 = (const float4*)w;
  int base = blockIdx.x * 256 + tid;
  float s = 0.f;
  for (int i = 0; i < 64; ++i) {
    float4 v = w4[base + i * 16384];
    s += fabsf(v.x) + fabsf(v.y) + fabsf(v.z) + fabsf(v.w);
  }
  s += __shfl_xor(s, 32); s += __shfl_xor(s, 16); s += __shfl_xor(s, 8);
  s += __shfl_xor(s, 4);  s += __shfl_xor(s, 2);  s += __shfl_xor(s, 1);
  __shared__ float red[4];
  int lane = tid & 63, wid = tid >> 6;
  if (lane == 0) red[wid] = s;
  __syncthreads();
  if (tid == 0) {
    double tot = (double)red[0] + (double)red[1] + (double)red[2] + (double)red[3];
    atomicAdd(&wsum[t], tot);
  }
}

// ---------------- weight ternary quant ----------------
__global__ __launch_bounds__(256) void wquant_kernel(const float* w0, const float* w1,
                                                     const float* w2, const float* w3,
                                                     unsigned short* wq, const double* wsum) {
  int t = blockIdx.y;
  const float* w = t == 0 ? w0 : t == 1 ? w1 : t == 2 ? w2 : w3;
  unsigned short* o = wq + (size_t)t * E * E;
  float mean = (float)(wsum[t] * (1.0 / 4194304.0));
  float wsc = fmaxf(mean, 1e-5f);
  float sw = 1.0f / wsc;
  int idx = (blockIdx.x * 256 + threadIdx.x) * 8;
  float4 a = *(const float4*)(w + idx);
  float4 b = *(const float4*)(w + idx + 4);
  float v[8] = {a.x, a.y, a.z, a.w, b.x, b.y, b.z, b.w};
  ushort8_t r;
#pragma unroll
  for (int j = 0; j < 8; ++j) {
    float q = rintf(v[j] * sw);
    q = fminf(fmaxf(q, -1.f), 1.f);
    r[j] = f2bf(q);
  }
  *(ushort8_t*)(o + idx) = r;
}

// ---------------- per-token int8 activation quant ----------------
__global__ __launch_bounds__(256) void actquant_kernel(const float* in, unsigned short* outq,
                                                       float* tokscale) {
  int tok = blockIdx.x;
  int tid = threadIdx.x;
  const float* row = in + (size_t)tok * E;
  float4 a = *(const float4*)(row + tid * 8);
  float4 b = *(const float4*)(row + tid * 8 + 4);
  float v[8] = {a.x, a.y, a.z, a.w, b.x, b.y, b.z, b.w};
  float am = 0.f;
#pragma unroll
  for (int j = 0; j < 8; ++j) am = fmaxf(am, fabsf(v[j]));
  am = fmaxf(am, __shfl_xor(am, 32)); am = fmaxf(am, __shfl_xor(am, 16));
  am = fmaxf(am, __shfl_xor(am, 8));  am = fmaxf(am, __shfl_xor(am, 4));
  am = fmaxf(am, __shfl_xor(am, 2));  am = fmaxf(am, __shfl_xor(am, 1));
  __shared__ float red[4];
  int lane = tid & 63, wid = tid >> 6;
  if (lane == 0) red[wid] = am;
  __syncthreads();
  am = fmaxf(fmaxf(red[0], red[1]), fmaxf(red[2], red[3]));
  float a_ = fmaxf(am, 1e-5f);
  float sx = 127.0f / a_;
  ushort8_t r;
#pragma unroll
  for (int j = 0; j < 8; ++j) {
    float q = rintf(v[j] * sx);
    q = fminf(fmaxf(q, -128.f), 127.f);
    r[j] = f2bf(q);
  }
  *(ushort8_t*)(outq + (size_t)tok * E + tid * 8) = r;
  if (tid == 0) tokscale[tok] = a_ / 127.0f;
}

// ---------------- bf16 exact-int GEMM with fused epilogue modes ----------------
// mode 0: C f32 [row][col]
// mode 1: hi/lo bf16 flat [row][col], scale *= extra (q: extra=1/sqrt(128))
// mode 3: hi/lo bf16 transposed vT [b][col][s]
__global__ __launch_bounds__(256) void gemm_bt_kernel(const unsigned short* A, const unsigned short* B,
                                                      float* C, unsigned short* Ohi, unsigned short* Olo,
                                                      const float* tokscale, const double* wsum,
                                                      int mode, float extra) {
  __shared__ unsigned short As[128 * 64];
  __shared__ unsigned short Bs[128 * 64];
  int tid = threadIdx.x;
  int lane = tid & 63, wid = tid >> 6;
  int bm = blockIdx.x >> 4, bn = blockIdx.x & 15;
  int wr = wid >> 1, wc = wid & 1;
  f32x4 acc[4][4];
#pragma unroll
  for (int i = 0; i < 4; ++i)
#pragma unroll
    for (int j = 0; j < 4; ++j) acc[i][j] = (f32x4){0.f, 0.f, 0.f, 0.f};

  for (int k0 = 0; k0 < E; k0 += 64) {
#pragma unroll
    for (int i = 0; i < 4; ++i) {
      int c = i * 256 + tid;
      int row = c >> 3, col = (c & 7) * 8;
      GLDS16(A + (size_t)(bm * 128 + row) * E + k0 + col, &As[(i * 256 + wid * 64) * 8]);
      GLDS16(B + (size_t)(bn * 128 + row) * E + k0 + col, &Bs[(i * 256 + wid * 64) * 8]);
    }
    __syncthreads();
#pragma unroll
    for (int kc = 0; kc < 2; ++kc) {
      short8 af[4], bf_[4];
#pragma unroll
      for (int mi = 0; mi < 4; ++mi)
        af[mi] = *(const short8*)&As[(wr * 64 + mi * 16 + (lane & 15)) * 64 + kc * 32 + (lane >> 4) * 8];
#pragma unroll
      for (int nj = 0; nj < 4; ++nj)
        bf_[nj] = *(const short8*)&Bs[(wc * 64 + nj * 16 + (lane & 15)) * 64 + kc * 32 + (lane >> 4) * 8];
#pragma unroll
      for (int mi = 0; mi < 4; ++mi)
#pragma unroll
        for (int nj = 0; nj < 4; ++nj)
          acc[mi][nj] = __builtin_amdgcn_mfma_f32_16x16x32_bf16(af[mi], bf_[nj], acc[mi][nj], 0, 0, 0);
    }
    __syncthreads();
  }

  float wsc = fmaxf((float)(wsum[0] * (1.0 / 4194304.0)), 1e-5f);
  int rbase = bm * 128 + wr * 64 + (lane >> 4) * 4;
  int cbase = bn * 128 + wc * 64 + (lane & 15);
  if (mode == 0) {
#pragma unroll
    for (int mi = 0; mi < 4; ++mi)
#pragma unroll
      for (int nj = 0; nj < 4; ++nj) {
        int row0 = rbase + mi * 16;
        int col = cbase + nj * 16;
#pragma unroll
        for (int r = 0; r < 4; ++r) {
          int row = row0 + r;
          C[(size_t)row * E + col] = acc[mi][nj][r] * tokscale[row] * wsc;
        }
      }
  } else if (mode == 1) {
#pragma unroll
    for (int mi = 0; mi < 4; ++mi)
#pragma unroll
      for (int nj = 0; nj < 4; ++nj) {
        int row0 = rbase + mi * 16;
        int col = cbase + nj * 16;
#pragma unroll
        for (int r = 0; r < 4; ++r) {
          int row = row0 + r;
          float v = acc[mi][nj][r] * tokscale[row] * wsc * extra;
          unsigned short hb = f2bf(v);
          Ohi[(size_t)row * E + col] = hb;
          Olo[(size_t)row * E + col] = f2bf(v - bf2f(hb));
        }
      }
  } else {  // mode 3: transposed vT [b][col][s]
#pragma unroll
    for (int mi = 0; mi < 4; ++mi)
#pragma unroll
      for (int nj = 0; nj < 4; ++nj) {
        int row0 = rbase + mi * 16;
        int col = cbase + nj * 16;
        ushort4_t h4, l4;
#pragma unroll
        for (int r = 0; r < 4; ++r) {
          float v = acc[mi][nj][r] * tokscale[row0 + r] * wsc;
          h4[r] = f2bf(v);
          l4[r] = f2bf(v - bf2f(h4[r]));
        }
        size_t off = ((size_t)((row0 >> 11) * 2048 + col)) * S + (row0 & 2047);
        *(ushort4_t*)(Ohi + off) = h4;
        *(ushort4_t*)(Olo + off) = l4;
      }
  }
}

// ---------------- flash attention v2: fragment-ordered async staging ----------------
// qhi/qlo/khi/klo: [4096][2048] bf16 (q pre-scaled by 1/sqrt(D))
// vthi/vtlo: [b(2)][2048 dglob][2048 s] bf16 ; ao: [4096][2048] f32
// Block: 256 thr / 4 waves; wave owns 32 q-rows (QBLK=128). KVBLK=32.
// Grid 512, id-permuted so CU c co-hosts q-blocks p and 15-p (balanced 68 tiles).
__global__ __launch_bounds__(256, 2) void attn2_kernel(
    const unsigned short* __restrict__ qhi, const unsigned short* __restrict__ qlo,
    const unsigned short* __restrict__ khi, const unsigned short* __restrict__ klo,
    const unsigned short* __restrict__ vthi, const unsigned short* __restrict__ vtlo,
    float* __restrict__ ao) {
  // LDS exactly 80KB -> 2 blocks/CU
  __shared__ __align__(16) unsigned short Kf[2][16][512];  // [buf][hl*8+st*4+kc][lane*8]
  __shared__ __align__(16) unsigned short Vf[2][16][512];  // [buf][hl*8+db][lane*8]
  __shared__ __align__(16) float Pl[4][1024];              // [wave][32 q][32 kv], XOR-swizzled

  int tid = threadIdx.x, lane = tid & 63, wid = tid >> 6;
  int g = lane >> 4, li = lane & 15;
  int id = blockIdx.x;
  int p = (id & 255) >> 5, bh = id & 31;
  int qb = (id >> 8) ? (15 - p) : p;
  int b = bh >> 4, h = bh & 15;
  size_t hoff = (size_t)h * 128;
  size_t vrow = (size_t)b * 2048 + h * 128;
  int qs = qb * 128;
  int nt = 4 * qb + 4;

  // Q fragments: wave rows qs + wid*32 + m*16 + li
  short8 qh[2][4], ql[2][4];
#pragma unroll
  for (int m = 0; m < 2; ++m) {
    size_t qoff = (size_t)(b * S + qs + wid * 32 + m * 16 + li) * E + hoff + g * 8;
#pragma unroll
    for (int kc = 0; kc < 4; ++kc) {
      qh[m][kc] = *(const short8*)(qhi + qoff + kc * 32);
      ql[m][kc] = *(const short8*)(qlo + qoff + kc * 32);
    }
  }

  f32x4 o[2][8];
#pragma unroll
  for (int m = 0; m < 2; ++m)
#pragma unroll
    for (int i = 0; i < 8; ++i) o[m][i] = (f32x4){0.f, 0.f, 0.f, 0.f};
  float m_[2][4], l_[2][4];
#pragma unroll
  for (int m = 0; m < 2; ++m)
#pragma unroll
    for (int r = 0; r < 4; ++r) { m_[m][r] = -__builtin_inff(); l_[m][r] = 0.f; }

  auto stage = [&](int buf, int kt) {
    int tok0 = b * S + kt * 32;
#pragma unroll
    for (int i = 0; i < 8; ++i) {
      int c = wid * 8 + i;
      if (c < 16) {  // K chunk: hl = c>>3, st = (c>>2)&1, kc = c&3
        int hl = c >> 3, st = (c >> 2) & 1, kc = c & 3;
        const unsigned short* src = (hl ? klo : khi)
            + (size_t)(tok0 + st * 16 + li) * E + hoff + kc * 32 + g * 8;
        GLDS16(src, &Kf[buf][c][0]);
      } else {       // V chunk: hl = (c-16)>>3, db = (c-16)&7
        int c2 = c - 16, hl = c2 >> 3, db = c2 & 7;
        const unsigned short* src = (hl ? vtlo : vthi)
            + (vrow + db * 16 + li) * (size_t)S + kt * 32 + g * 8;
        GLDS16(src, &Vf[buf][c2][0]);
      }
    }
  };

  stage(0, 0);
  for (int kt = 0; kt < nt; ++kt) {
    int buf = kt & 1;
    __syncthreads();                 // drains this wave's stage(kt); joins all waves
    if (kt + 1 < nt) stage(buf ^ 1, kt + 1);

    // ---- QK^T (hi*hi + hi*lo + lo*hi) ----
    f32x4 s2[2][2];
#pragma unroll
    for (int m = 0; m < 2; ++m)
#pragma unroll
      for (int st = 0; st < 2; ++st) s2[m][st] = (f32x4){0.f, 0.f, 0.f, 0.f};
#pragma unroll
    for (int st = 0; st < 2; ++st)
#pragma unroll
      for (int kc = 0; kc < 4; ++kc) {
        short8 kh = *(const short8*)&Kf[buf][st * 4 + kc][lane * 8];
        short8 kl = *(const short8*)&Kf[buf][8 + st * 4 + kc][lane * 8];
#pragma unroll
        for (int m = 0; m < 2; ++m) {
          s2[m][st] = __builtin_amdgcn_mfma_f32_16x16x32_bf16(qh[m][kc], kh, s2[m][st], 0, 0, 0);
          s2[m][st] = __builtin_amdgcn_mfma_f32_16x16x32_bf16(qh[m][kc], kl, s2[m][st], 0, 0, 0);
          s2[m][st] = __builtin_amdgcn_mfma_f32_16x16x32_bf16(ql[m][kc], kh, s2[m][st], 0, 0, 0);
        }
      }

    // ---- causal mask (wave-uniform skip for interior tiles) ----
    if (kt * 32 + 31 > qs + wid * 32) {
#pragma unroll
      for (int m = 0; m < 2; ++m)
#pragma unroll
        for (int st = 0; st < 2; ++st)
#pragma unroll
          for (int r = 0; r < 4; ++r) {
            int kvg = kt * 32 + st * 16 + li;
            int qg = qs + wid * 32 + m * 16 + g * 4 + r;
            if (kvg > qg) s2[m][st][r] = -1e30f;
          }
    }

    // ---- online softmax + P write + o rescale ----
#pragma unroll
    for (int m = 0; m < 2; ++m) {
      float mn[4], al[4];
#pragma unroll
      for (int r = 0; r < 4; ++r) {
        float mloc = fmaxf(s2[m][0][r], s2[m][1][r]);
        mloc = fmaxf(mloc, __shfl_xor(mloc, 1));
        mloc = fmaxf(mloc, __shfl_xor(mloc, 2));
        mloc = fmaxf(mloc, __shfl_xor(mloc, 4));
        mloc = fmaxf(mloc, __shfl_xor(mloc, 8));
        mn[r] = fmaxf(m_[m][r], mloc);
        al[r] = expf(m_[m][r] - mn[r]);
        m_[m][r] = mn[r];
      }
#pragma unroll
      for (int st = 0; st < 2; ++st)
#pragma unroll
        for (int r = 0; r < 4; ++r) s2[m][st][r] = expf(s2[m][st][r] - mn[r]);
#pragma unroll
      for (int r = 0; r < 4; ++r) {
        float ps = s2[m][0][r] + s2[m][1][r];
        ps += __shfl_xor(ps, 1); ps += __shfl_xor(ps, 2);
        ps += __shfl_xor(ps, 4); ps += __shfl_xor(ps, 8);
        l_[m][r] = l_[m][r] * al[r] + ps;
      }
#pragma unroll
      for (int st = 0; st < 2; ++st)
#pragma unroll
        for (int r = 0; r < 4; ++r) {
          int qrow = m * 16 + g * 4 + r;
          int byte = (qrow * 32 + st * 16 + li) * 4;
          byte ^= (qrow & 7) << 4;
          *(float*)((char*)&Pl[wid][0] + byte) = s2[m][st][r];
        }
#pragma unroll
      for (int db = 0; db < 8; ++db)
#pragma unroll
        for (int r = 0; r < 4; ++r) o[m][db][r] *= al[r];
    }

    // ---- P -> hi/lo A-fragments ----
    short8 pah[2], pal[2];
#pragma unroll
    for (int m = 0; m < 2; ++m) {
      int q = m * 16 + li;
      int swz = (q & 7) << 4;
      int b0 = q * 128 + g * 32;
      float4 p0 = *(const float4*)((char*)&Pl[wid][0] + (b0 ^ swz));
      float4 p1 = *(const float4*)((char*)&Pl[wid][0] + ((b0 + 16) ^ swz));
      float pv[8] = {p0.x, p0.y, p0.z, p0.w, p1.x, p1.y, p1.z, p1.w};
#pragma unroll
      for (int j = 0; j < 8; ++j) {
        unsigned short hb = f2bf(pv[j]);
        pah[m][j] = (short)hb;
        pal[m][j] = (short)f2bf(pv[j] - bf2f(hb));
      }
    }

    // ---- PV (hi/lo split) ----
#pragma unroll
    for (int db = 0; db < 8; ++db) {
      short8 vh = *(const short8*)&Vf[buf][db][lane * 8];
      short8 vl = *(const short8*)&Vf[buf][8 + db][lane * 8];
#pragma unroll
      for (int m = 0; m < 2; ++m) {
        o[m][db] = __builtin_amdgcn_mfma_f32_16x16x32_bf16(pah[m], vh, o[m][db], 0, 0, 0);
        o[m][db] = __builtin_amdgcn_mfma_f32_16x16x32_bf16(pah[m], vl, o[m][db], 0, 0, 0);
        o[m][db] = __builtin_amdgcn_mfma_f32_16x16x32_bf16(pal[m], vh, o[m][db], 0, 0, 0);
      }
    }
  }

  // ---- epilogue ----
#pragma unroll
  for (int m = 0; m < 2; ++m) {
    float linv[4];
#pragma unroll
    for (int r = 0; r < 4; ++r) linv[r] = 1.0f / l_[m][r];
#pragma unroll
    for (int db = 0; db < 8; ++db)
#pragma unroll
      for (int r = 0; r < 4; ++r) {
        size_t row = (size_t)(b * S + qs + wid * 32 + m * 16 + g * 4 + r);
        ao[row * E + hoff + db * 16 + li] = o[m][db][r] * linv[r];
      }
  }
}

// ---------------- launch ----------------
extern "C" void kernel_launch(void* const* d_in, const int* in_sizes, int n_in,
                              void* d_out, int out_size, void* d_ws, size_t ws_size,
                              hipStream_t stream) {
  (void)in_sizes; (void)n_in; (void)out_size; (void)ws_size;
  const float* x  = (const float*)d_in[0];
  const float* w0 = (const float*)d_in[1];
  const float* w1 = (const float*)d_in[2];
  const float* w2 = (const float*)d_in[3];
  const float* w3 = (const float*)d_in[4];
  float* out = (float*)d_out;
  char* ws = (char*)d_ws;

  const float invs = 0.088388347648318447f;  // fp32(1/sqrt(128))
  size_t WQB = (size_t)E * E;
  size_t TE  = (size_t)TOK * E;

  double* wsum = (double*)ws;                         // 32 B
  float* tsx   = (float*)(ws + 256);                  // 16 KB
  float* tsa   = (float*)(ws + 256 + 16384);          // 16 KB
  unsigned short* wq   = (unsigned short*)(ws + 33024);
  unsigned short* xq   = wq + 4 * WQB;
  unsigned short* qhi  = xq + TE;
  unsigned short* qlo  = qhi + TE;
  unsigned short* khi  = qlo + TE;
  unsigned short* klo  = khi + TE;
  unsigned short* vthi = klo + TE;
  unsigned short* vtlo = vthi + TE;
  float* aof = (float*)(vtlo + TE);
  unsigned short* aq = xq;                            // alias: xq dead after v-GEMM

  hipMemsetAsync(ws, 0, 64, stream);
  wabs_kernel<<<dim3(64, 4), 256, 0, stream>>>(w0, w1, w2, w3, wsum);
  wquant_kernel<<<dim3(2048, 4), 256, 0, stream>>>(w0, w1, w2, w3, wq, wsum);
  actquant_kernel<<<TOK, 256, 0, stream>>>(x, xq, tsx);
  gemm_bt_kernel<<<512, 256, 0, stream>>>(xq, wq + 0 * WQB, nullptr, qhi, qlo, tsx, wsum + 0, 1, invs);
  gemm_bt_kernel<<<512, 256, 0, stream>>>(xq, wq + 1 * WQB, nullptr, khi, klo, tsx, wsum + 1, 1, 1.0f);
  gemm_bt_kernel<<<512, 256, 0, stream>>>(xq, wq + 2 * WQB, nullptr, vthi, vtlo, tsx, wsum + 2, 3, 1.0f);
  attn2_kernel<<<512, 256, 0, stream>>>(qhi, qlo, khi, klo, vthi, vtlo, aof);
  actquant_kernel<<<TOK, 256, 0, stream>>>(aof, aq, tsa);
  gemm_bt_kernel<<<512, 256, 0, stream>>>(aq, wq + 3 * WQB, out, nullptr, nullptr, tsa, wsum + 3, 0, 1.0f);
}

// Round 4
// 604.812 us; speedup vs baseline: 1.3728x; 1.3348x over previous
//
#include <hip/hip_runtime.h>
#include <hip/hip_bf16.h>
#include <stdint.h>
#include <stddef.h>

#define DI __device__ __forceinline__

typedef __attribute__((ext_vector_type(8))) short short8;
typedef __attribute__((ext_vector_type(4))) float f32x4;
typedef __attribute__((ext_vector_type(4))) int i32x4;
typedef __attribute__((ext_vector_type(4))) unsigned short ushort4_t;
typedef __attribute__((ext_vector_type(8))) unsigned short ushort8_t;
typedef __attribute__((ext_vector_type(8))) char char8;

constexpr int E = 2048;
constexpr int TOK = 4096;   // B*S
constexpr int S = 2048;

// RNE float->bf16 (finite values only; matches jnp/HW round-to-nearest-even)
DI unsigned short f2bf(float f) {
  unsigned u = __builtin_bit_cast(unsigned, f);
  unsigned r = (u + 0x7FFFu + ((u >> 16) & 1u)) >> 16;
  return (unsigned short)r;
}
DI float bf2f(unsigned short h) {
  unsigned u = ((unsigned)h) << 16;
  return __builtin_bit_cast(float, u);
}

#define GLDS16(gp, lp) __builtin_amdgcn_global_load_lds( \
    (const __attribute__((address_space(1))) void*)(gp), \
    (__attribute__((address_space(3))) void*)(lp), 16, 0, 0)

// ---------------- weight absmean sum ----------------
__global__ __launch_bounds__(256) void wabs_kernel(const float* w0, const float* w1,
                                                   const float* w2, const float* w3,
                                                   double* wsum) {
  int t = blockIdx.y;
  const float* w = t == 0 ? w0 : t == 1 ? w1 : t == 2 ? w2 : w3;
  int tid = threadIdx.x;
  const float4* w4 = (const float4*)w;
  int base = blockIdx.x * 256 + tid;
  float s = 0.f;
  for (int i = 0; i < 64; ++i) {
    float4 v = w4[base + i * 16384];
    s += fabsf(v.x) + fabsf(v.y) + fabsf(v.z) + fabsf(v.w);
  }
  s += __shfl_xor(s, 32); s += __shfl_xor(s, 16); s += __shfl_xor(s, 8);
  s += __shfl_xor(s, 4);  s += __shfl_xor(s, 2);  s += __shfl_xor(s, 1);
  __shared__ float red[4];
  int lane = tid & 63, wid = tid >> 6;
  if (lane == 0) red[wid] = s;
  __syncthreads();
  if (tid == 0) {
    double tot = (double)red[0] + (double)red[1] + (double)red[2] + (double)red[3];
    atomicAdd(&wsum[t], tot);
  }
}

// ---------------- weight ternary quant -> int8 ----------------
__global__ __launch_bounds__(256) void wquant_kernel(const float* w0, const float* w1,
                                                     const float* w2, const float* w3,
                                                     char* wq, const double* wsum) {
  int t = blockIdx.y;
  const float* w = t == 0 ? w0 : t == 1 ? w1 : t == 2 ? w2 : w3;
  char* o = wq + (size_t)t * E * E;
  float mean = (float)(wsum[t] * (1.0 / 4194304.0));
  float wsc = fmaxf(mean, 1e-5f);
  float sw = 1.0f / wsc;
  int idx = (blockIdx.x * 256 + threadIdx.x) * 8;
  float4 a = *(const float4*)(w + idx);
  float4 b = *(const float4*)(w + idx + 4);
  float v[8] = {a.x, a.y, a.z, a.w, b.x, b.y, b.z, b.w};
  char8 r;
#pragma unroll
  for (int j = 0; j < 8; ++j) {
    float q = rintf(v[j] * sw);
    q = fminf(fmaxf(q, -1.f), 1.f);
    r[j] = (char)(int)q;
  }
  *(char8*)(o + idx) = r;
}

// ---------------- per-token int8 activation quant -> int8 ----------------
__global__ __launch_bounds__(256) void actquant_kernel(const float* in, char* outq,
                                                       float* tokscale) {
  int tok = blockIdx.x;
  int tid = threadIdx.x;
  const float* row = in + (size_t)tok * E;
  float4 a = *(const float4*)(row + tid * 8);
  float4 b = *(const float4*)(row + tid * 8 + 4);
  float v[8] = {a.x, a.y, a.z, a.w, b.x, b.y, b.z, b.w};
  float am = 0.f;
#pragma unroll
  for (int j = 0; j < 8; ++j) am = fmaxf(am, fabsf(v[j]));
  am = fmaxf(am, __shfl_xor(am, 32)); am = fmaxf(am, __shfl_xor(am, 16));
  am = fmaxf(am, __shfl_xor(am, 8));  am = fmaxf(am, __shfl_xor(am, 4));
  am = fmaxf(am, __shfl_xor(am, 2));  am = fmaxf(am, __shfl_xor(am, 1));
  __shared__ float red[4];
  int lane = tid & 63, wid = tid >> 6;
  if (lane == 0) red[wid] = am;
  __syncthreads();
  am = fmaxf(fmaxf(red[0], red[1]), fmaxf(red[2], red[3]));
  float a_ = fmaxf(am, 1e-5f);
  float sx = 127.0f / a_;
  char8 r;
#pragma unroll
  for (int j = 0; j < 8; ++j) {
    float q = rintf(v[j] * sx);
    q = fminf(fmaxf(q, -128.f), 127.f);
    r[j] = (char)(int)q;
  }
  *(char8*)(outq + (size_t)tok * E + tid * 8) = r;
  if (tid == 0) tokscale[tok] = a_ / 127.0f;
}

// ---------------- int8 exact GEMM: C[M][N] = (A[M][K] . B[N][K]^T) * ts[row]*wsc*extra
// mode 0: C f32 [row][col]
// mode 1: hi/lo bf16 flat [row][col]
// mode 3: hi/lo bf16 transposed vT [b][col][s]
__global__ __launch_bounds__(256) void gemm_i8_kernel(const char* A, const char* B,
                                                      float* C, unsigned short* Ohi, unsigned short* Olo,
                                                      const float* tokscale, const double* wsum,
                                                      int mode, float extra) {
  __shared__ __align__(16) char As[128 * 128];
  __shared__ __align__(16) char Bs[128 * 128];
  int tid = threadIdx.x;
  int lane = tid & 63, wid = tid >> 6;
  int bm = blockIdx.x >> 4, bn = blockIdx.x & 15;
  int wr = wid >> 1, wc = wid & 1;
  i32x4 acc[4][4];
#pragma unroll
  for (int i = 0; i < 4; ++i)
#pragma unroll
    for (int j = 0; j < 4; ++j) acc[i][j] = (i32x4){0, 0, 0, 0};

  for (int k0 = 0; k0 < E; k0 += 128) {
#pragma unroll
    for (int i = 0; i < 4; ++i) {
      int c = i * 256 + tid;                    // 1024 16B-chunks per tile
      int row = c >> 3, col = (c & 7) * 16;
      GLDS16(A + (size_t)(bm * 128 + row) * E + k0 + col, &As[(i * 256 + wid * 64) * 16]);
      GLDS16(B + (size_t)(bn * 128 + row) * E + k0 + col, &Bs[(i * 256 + wid * 64) * 16]);
    }
    __syncthreads();
#pragma unroll
    for (int kc = 0; kc < 2; ++kc) {
      i32x4 af[4], bf_[4];
#pragma unroll
      for (int mi = 0; mi < 4; ++mi)
        af[mi] = *(const i32x4*)&As[(wr * 64 + mi * 16 + (lane & 15)) * 128 + kc * 64 + (lane >> 4) * 16];
#pragma unroll
      for (int nj = 0; nj < 4; ++nj)
        bf_[nj] = *(const i32x4*)&Bs[(wc * 64 + nj * 16 + (lane & 15)) * 128 + kc * 64 + (lane >> 4) * 16];
#pragma unroll
      for (int mi = 0; mi < 4; ++mi)
#pragma unroll
        for (int nj = 0; nj < 4; ++nj)
          acc[mi][nj] = __builtin_amdgcn_mfma_i32_16x16x64_i8(af[mi], bf_[nj], acc[mi][nj], 0, 0, 0);
    }
    __syncthreads();
  }

  float wsc = fmaxf((float)(wsum[0] * (1.0 / 4194304.0)), 1e-5f);
  int rbase = bm * 128 + wr * 64 + (lane >> 4) * 4;
  int cbase = bn * 128 + wc * 64 + (lane & 15);
  if (mode == 0) {
#pragma unroll
    for (int mi = 0; mi < 4; ++mi)
#pragma unroll
      for (int nj = 0; nj < 4; ++nj) {
        int row0 = rbase + mi * 16;
        int col = cbase + nj * 16;
#pragma unroll
        for (int r = 0; r < 4; ++r) {
          int row = row0 + r;
          C[(size_t)row * E + col] = (float)acc[mi][nj][r] * tokscale[row] * wsc * extra;
        }
      }
  } else if (mode == 1) {
#pragma unroll
    for (int mi = 0; mi < 4; ++mi)
#pragma unroll
      for (int nj = 0; nj < 4; ++nj) {
        int row0 = rbase + mi * 16;
        int col = cbase + nj * 16;
#pragma unroll
        for (int r = 0; r < 4; ++r) {
          int row = row0 + r;
          float v = (float)acc[mi][nj][r] * tokscale[row] * wsc * extra;
          unsigned short hb = f2bf(v);
          Ohi[(size_t)row * E + col] = hb;
          Olo[(size_t)row * E + col] = f2bf(v - bf2f(hb));
        }
      }
  } else {  // mode 3: transposed vT [b][col][s]
#pragma unroll
    for (int mi = 0; mi < 4; ++mi)
#pragma unroll
      for (int nj = 0; nj < 4; ++nj) {
        int row0 = rbase + mi * 16;
        int col = cbase + nj * 16;
        ushort4_t h4, l4;
#pragma unroll
        for (int r = 0; r < 4; ++r) {
          float v = (float)acc[mi][nj][r] * tokscale[row0 + r] * wsc * extra;
          h4[r] = f2bf(v);
          l4[r] = f2bf(v - bf2f(h4[r]));
        }
        size_t off = ((size_t)((row0 >> 11) * 2048 + col)) * S + (row0 & 2047);
        *(ushort4_t*)(Ohi + off) = h4;
        *(ushort4_t*)(Olo + off) = l4;
      }
  }
}

// ---------------- flash attention: fragment-ordered async staging + defer-max + setprio ----
// qhi/qlo/khi/klo: [4096][2048] bf16 (q pre-scaled by 1/sqrt(D))
// vthi/vtlo: [b(2)][2048 dglob][2048 s] bf16 ; ao: [4096][2048] f32
__global__ __launch_bounds__(256, 2) void attn2_kernel(
    const unsigned short* __restrict__ qhi, const unsigned short* __restrict__ qlo,
    const unsigned short* __restrict__ khi, const unsigned short* __restrict__ klo,
    const unsigned short* __restrict__ vthi, const unsigned short* __restrict__ vtlo,
    float* __restrict__ ao) {
  __shared__ __align__(16) unsigned short Kf[2][16][512];  // [buf][hl*8+st*4+kc][lane*8]
  __shared__ __align__(16) unsigned short Vf[2][16][512];  // [buf][hl*8+db][lane*8]
  __shared__ __align__(16) float Pl[4][1024];              // [wave][32 q][32 kv], XOR-swizzled

  int tid = threadIdx.x, lane = tid & 63, wid = tid >> 6;
  int g = lane >> 4, li = lane & 15;
  int id = blockIdx.x;
  int p = (id & 255) >> 5, bh = id & 31;
  int qb = (id >> 8) ? (15 - p) : p;
  int b = bh >> 4, h = bh & 15;
  size_t hoff = (size_t)h * 128;
  size_t vrow = (size_t)b * 2048 + h * 128;
  int qs = qb * 128;
  int nt = 4 * qb + 4;

  short8 qh[2][4], ql[2][4];
#pragma unroll
  for (int m = 0; m < 2; ++m) {
    size_t qoff = (size_t)(b * S + qs + wid * 32 + m * 16 + li) * E + hoff + g * 8;
#pragma unroll
    for (int kc = 0; kc < 4; ++kc) {
      qh[m][kc] = *(const short8*)(qhi + qoff + kc * 32);
      ql[m][kc] = *(const short8*)(qlo + qoff + kc * 32);
    }
  }

  f32x4 o[2][8];
#pragma unroll
  for (int m = 0; m < 2; ++m)
#pragma unroll
    for (int i = 0; i < 8; ++i) o[m][i] = (f32x4){0.f, 0.f, 0.f, 0.f};
  float m_[2][4], l_[2][4];
#pragma unroll
  for (int m = 0; m < 2; ++m)
#pragma unroll
    for (int r = 0; r < 4; ++r) { m_[m][r] = -__builtin_inff(); l_[m][r] = 0.f; }

  auto stage = [&](int buf, int kt) {
    int tok0 = b * S + kt * 32;
#pragma unroll
    for (int i = 0; i < 8; ++i) {
      int c = wid * 8 + i;
      if (c < 16) {
        int hl = c >> 3, st = (c >> 2) & 1, kc = c & 3;
        const unsigned short* src = (hl ? klo : khi)
            + (size_t)(tok0 + st * 16 + li) * E + hoff + kc * 32 + g * 8;
        GLDS16(src, &Kf[buf][c][0]);
      } else {
        int c2 = c - 16, hl = c2 >> 3, db = c2 & 7;
        const unsigned short* src = (hl ? vtlo : vthi)
            + (vrow + db * 16 + li) * (size_t)S + kt * 32 + g * 8;
        GLDS16(src, &Vf[buf][c2][0]);
      }
    }
  };

  stage(0, 0);
  for (int kt = 0; kt < nt; ++kt) {
    int buf = kt & 1;
    __syncthreads();
    if (kt + 1 < nt) stage(buf ^ 1, kt + 1);

    // ---- QK^T (hi*hi + hi*lo + lo*hi) ----
    f32x4 s2[2][2];
#pragma unroll
    for (int m = 0; m < 2; ++m)
#pragma unroll
      for (int st = 0; st < 2; ++st) s2[m][st] = (f32x4){0.f, 0.f, 0.f, 0.f};
    __builtin_amdgcn_s_setprio(1);
#pragma unroll
    for (int st = 0; st < 2; ++st)
#pragma unroll
      for (int kc = 0; kc < 4; ++kc) {
        short8 kh = *(const short8*)&Kf[buf][st * 4 + kc][lane * 8];
        short8 kl = *(const short8*)&Kf[buf][8 + st * 4 + kc][lane * 8];
#pragma unroll
        for (int m = 0; m < 2; ++m) {
          s2[m][st] = __builtin_amdgcn_mfma_f32_16x16x32_bf16(qh[m][kc], kh, s2[m][st], 0, 0, 0);
          s2[m][st] = __builtin_amdgcn_mfma_f32_16x16x32_bf16(qh[m][kc], kl, s2[m][st], 0, 0, 0);
          s2[m][st] = __builtin_amdgcn_mfma_f32_16x16x32_bf16(ql[m][kc], kh, s2[m][st], 0, 0, 0);
        }
      }
    __builtin_amdgcn_s_setprio(0);

    // ---- causal mask ----
    if (kt * 32 + 31 > qs + wid * 32) {
#pragma unroll
      for (int m = 0; m < 2; ++m)
#pragma unroll
        for (int st = 0; st < 2; ++st)
#pragma unroll
          for (int r = 0; r < 4; ++r) {
            int kvg = kt * 32 + st * 16 + li;
            int qg = qs + wid * 32 + m * 16 + g * 4 + r;
            if (kvg > qg) s2[m][st][r] = -1e30f;
          }
    }

    // ---- online softmax with defer-max (THR=8) ----
    float mloc[2][4];
#pragma unroll
    for (int m = 0; m < 2; ++m)
#pragma unroll
      for (int r = 0; r < 4; ++r) {
        float t = fmaxf(s2[m][0][r], s2[m][1][r]);
        t = fmaxf(t, __shfl_xor(t, 1));
        t = fmaxf(t, __shfl_xor(t, 2));
        t = fmaxf(t, __shfl_xor(t, 4));
        t = fmaxf(t, __shfl_xor(t, 8));
        mloc[m][r] = t;
      }
    float need = -1e38f;
#pragma unroll
    for (int m = 0; m < 2; ++m)
#pragma unroll
      for (int r = 0; r < 4; ++r) need = fmaxf(need, mloc[m][r] - m_[m][r]);
    bool fast = (__ballot(need <= 8.0f) == ~0ULL);
    if (!fast) {
#pragma unroll
      for (int m = 0; m < 2; ++m)
#pragma unroll
        for (int r = 0; r < 4; ++r) {
          float mn = fmaxf(m_[m][r], mloc[m][r]);
          float al = expf(m_[m][r] - mn);
          m_[m][r] = mn;
          l_[m][r] *= al;
#pragma unroll
          for (int db = 0; db < 8; ++db) o[m][db][r] *= al;
        }
    }
#pragma unroll
    for (int m = 0; m < 2; ++m) {
#pragma unroll
      for (int st = 0; st < 2; ++st)
#pragma unroll
        for (int r = 0; r < 4; ++r) s2[m][st][r] = expf(s2[m][st][r] - m_[m][r]);
#pragma unroll
      for (int r = 0; r < 4; ++r) {
        float ps = s2[m][0][r] + s2[m][1][r];
        ps += __shfl_xor(ps, 1); ps += __shfl_xor(ps, 2);
        ps += __shfl_xor(ps, 4); ps += __shfl_xor(ps, 8);
        l_[m][r] += ps;
      }
#pragma unroll
      for (int st = 0; st < 2; ++st)
#pragma unroll
        for (int r = 0; r < 4; ++r) {
          int qrow = m * 16 + g * 4 + r;
          int byte = (qrow * 32 + st * 16 + li) * 4;
          byte ^= (qrow & 7) << 4;
          *(float*)((char*)&Pl[wid][0] + byte) = s2[m][st][r];
        }
    }

    // ---- P -> hi/lo A-fragments ----
    short8 pah[2], pal[2];
#pragma unroll
    for (int m = 0; m < 2; ++m) {
      int q = m * 16 + li;
      int swz = (q & 7) << 4;
      int b0 = q * 128 + g * 32;
      float4 p0 = *(const float4*)((char*)&Pl[wid][0] + (b0 ^ swz));
      float4 p1 = *(const float4*)((char*)&Pl[wid][0] + ((b0 + 16) ^ swz));
      float pv[8] = {p0.x, p0.y, p0.z, p0.w, p1.x, p1.y, p1.z, p1.w};
#pragma unroll
      for (int j = 0; j < 8; ++j) {
        unsigned short hb = f2bf(pv[j]);
        pah[m][j] = (short)hb;
        pal[m][j] = (short)f2bf(pv[j] - bf2f(hb));
      }
    }

    // ---- PV (hi/lo split) ----
    __builtin_amdgcn_s_setprio(1);
#pragma unroll
    for (int db = 0; db < 8; ++db) {
      short8 vh = *(const short8*)&Vf[buf][db][lane * 8];
      short8 vl = *(const short8*)&Vf[buf][8 + db][lane * 8];
#pragma unroll
      for (int m = 0; m < 2; ++m) {
        o[m][db] = __builtin_amdgcn_mfma_f32_16x16x32_bf16(pah[m], vh, o[m][db], 0, 0, 0);
        o[m][db] = __builtin_amdgcn_mfma_f32_16x16x32_bf16(pah[m], vl, o[m][db], 0, 0, 0);
        o[m][db] = __builtin_amdgcn_mfma_f32_16x16x32_bf16(pal[m], vh, o[m][db], 0, 0, 0);
      }
    }
    __builtin_amdgcn_s_setprio(0);
  }

  // ---- epilogue ----
#pragma unroll
  for (int m = 0; m < 2; ++m) {
    float linv[4];
#pragma unroll
    for (int r = 0; r < 4; ++r) linv[r] = 1.0f / l_[m][r];
#pragma unroll
    for (int db = 0; db < 8; ++db)
#pragma unroll
      for (int r = 0; r < 4; ++r) {
        size_t row = (size_t)(b * S + qs + wid * 32 + m * 16 + g * 4 + r);
        ao[row * E + hoff + db * 16 + li] = o[m][db][r] * linv[r];
      }
  }
}

// ---------------- launch ----------------
extern "C" void kernel_launch(void* const* d_in, const int* in_sizes, int n_in,
                              void* d_out, int out_size, void* d_ws, size_t ws_size,
                              hipStream_t stream) {
  (void)in_sizes; (void)n_in; (void)out_size; (void)ws_size;
  const float* x  = (const float*)d_in[0];
  const float* w0 = (const float*)d_in[1];
  const float* w1 = (const float*)d_in[2];
  const float* w2 = (const float*)d_in[3];
  const float* w3 = (const float*)d_in[4];
  float* out = (float*)d_out;
  char* ws = (char*)d_ws;

  const float invs = 0.088388347648318447f;  // fp32(1/sqrt(128))
  size_t WQB = (size_t)E * E;                 // bytes per int8 weight matrix
  size_t TE  = (size_t)TOK * E;

  double* wsum = (double*)ws;                         // 32 B
  float* tsx   = (float*)(ws + 256);                  // 16 KB
  float* tsa   = (float*)(ws + 256 + 16384);          // 16 KB
  char* wq   = ws + 33024;                            // 4 x 4.19 MB int8
  char* xq   = wq + 4 * WQB;                          // 8.39 MB int8
  unsigned short* qhi  = (unsigned short*)(xq + TE);  // 6 x 16.78 MB bf16
  unsigned short* qlo  = qhi + TE;
  unsigned short* khi  = qlo + TE;
  unsigned short* klo  = khi + TE;
  unsigned short* vthi = klo + TE;
  unsigned short* vtlo = vthi + TE;
  float* aof = (float*)(vtlo + TE);                   // 33.55 MB
  char* aq = xq;                                      // alias: xq dead after v-GEMM

  hipMemsetAsync(ws, 0, 64, stream);
  wabs_kernel<<<dim3(64, 4), 256, 0, stream>>>(w0, w1, w2, w3, wsum);
  wquant_kernel<<<dim3(2048, 4), 256, 0, stream>>>(w0, w1, w2, w3, wq, wsum);
  actquant_kernel<<<TOK, 256, 0, stream>>>(x, xq, tsx);
  gemm_i8_kernel<<<512, 256, 0, stream>>>(xq, wq + 0 * WQB, nullptr, qhi, qlo, tsx, wsum + 0, 1, invs);
  gemm_i8_kernel<<<512, 256, 0, stream>>>(xq, wq + 1 * WQB, nullptr, khi, klo, tsx, wsum + 1, 1, 1.0f);
  gemm_i8_kernel<<<512, 256, 0, stream>>>(xq, wq + 2 * WQB, nullptr, vthi, vtlo, tsx, wsum + 2, 3, 1.0f);
  attn2_kernel<<<512, 256, 0, stream>>>(qhi, qlo, khi, klo, vthi, vtlo, aof);
  actquant_kernel<<<TOK, 256, 0, stream>>>(aof, aq, tsa);
  gemm_i8_kernel<<<512, 256, 0, stream>>>(aq, wq + 3 * WQB, out, nullptr, nullptr, tsa, wsum + 3, 0, 1.0f);
}

// Round 8
// 463.705 us; speedup vs baseline: 1.7906x; 1.3043x over previous
//
#include <hip/hip_runtime.h>
#include <hip/hip_bf16.h>
#include <stdint.h>
#include <stddef.h>

#define DI __device__ __forceinline__

typedef __attribute__((ext_vector_type(8))) short short8;
typedef __attribute__((ext_vector_type(4))) float f32x4;
typedef __attribute__((ext_vector_type(16))) float f32x16;
typedef __attribute__((ext_vector_type(4))) int i32x4;
typedef __attribute__((ext_vector_type(2))) unsigned u32x2;
typedef __attribute__((ext_vector_type(4))) unsigned short ushort4_t;
typedef __attribute__((ext_vector_type(8))) unsigned short ushort8_t;
typedef __attribute__((ext_vector_type(8))) char char8;

constexpr int E = 2048;
constexpr int TOK = 4096;   // B*S
constexpr int S = 2048;

// RNE float->bf16 (finite values only; matches jnp/HW round-to-nearest-even)
DI unsigned short f2bf(float f) {
  unsigned u = __builtin_bit_cast(unsigned, f);
  unsigned r = (u + 0x7FFFu + ((u >> 16) & 1u)) >> 16;
  return (unsigned short)r;
}
DI float bf2f(unsigned short h) {
  unsigned u = ((unsigned)h) << 16;
  return __builtin_bit_cast(float, u);
}

#define GLDS16(gp, lp) __builtin_amdgcn_global_load_lds( \
    (const __attribute__((address_space(1))) void*)(gp), \
    (__attribute__((address_space(3))) void*)(lp), 16, 0, 0)

// ---------------- weight absmean sum ----------------
__global__ __launch_bounds__(256) void wabs_kernel(const float* w0, const float* w1,
                                                   const float* w2, const float* w3,
                                                   double* wsum) {
  int t = blockIdx.y;
  const float* w = t == 0 ? w0 : t == 1 ? w1 : t == 2 ? w2 : w3;
  int tid = threadIdx.x;
  const float4* w4 = (const float4*)w;
  int base = blockIdx.x * 256 + tid;
  float s = 0.f;
  for (int i = 0; i < 64; ++i) {
    float4 v = w4[base + i * 16384];
    s += fabsf(v.x) + fabsf(v.y) + fabsf(v.z) + fabsf(v.w);
  }
  s += __shfl_xor(s, 32); s += __shfl_xor(s, 16); s += __shfl_xor(s, 8);
  s += __shfl_xor(s, 4);  s += __shfl_xor(s, 2);  s += __shfl_xor(s, 1);
  __shared__ float red[4];
  int lane = tid & 63, wid = tid >> 6;
  if (lane == 0) red[wid] = s;
  __syncthreads();
  if (tid == 0) {
    double tot = (double)red[0] + (double)red[1] + (double)red[2] + (double)red[3];
    atomicAdd(&wsum[t], tot);
  }
}

// ---------------- weight ternary quant -> int8 ----------------
__global__ __launch_bounds__(256) void wquant_kernel(const float* w0, const float* w1,
                                                     const float* w2, const float* w3,
                                                     char* wq, const double* wsum) {
  int t = blockIdx.y;
  const float* w = t == 0 ? w0 : t == 1 ? w1 : t == 2 ? w2 : w3;
  char* o = wq + (size_t)t * E * E;
  float mean = (float)(wsum[t] * (1.0 / 4194304.0));
  float wsc = fmaxf(mean, 1e-5f);
  float sw = 1.0f / wsc;
  int idx = (blockIdx.x * 256 + threadIdx.x) * 8;
  float4 a = *(const float4*)(w + idx);
  float4 b = *(const float4*)(w + idx + 4);
  float v[8] = {a.x, a.y, a.z, a.w, b.x, b.y, b.z, b.w};
  char8 r;
#pragma unroll
  for (int j = 0; j < 8; ++j) {
    float q = rintf(v[j] * sw);
    q = fminf(fmaxf(q, -1.f), 1.f);
    r[j] = (char)(int)q;
  }
  *(char8*)(o + idx) = r;
}

// ---------------- per-token int8 activation quant -> int8 ----------------
__global__ __launch_bounds__(256) void actquant_kernel(const float* in, char* outq,
                                                       float* tokscale) {
  int tok = blockIdx.x;
  int tid = threadIdx.x;
  const float* row = in + (size_t)tok * E;
  float4 a = *(const float4*)(row + tid * 8);
  float4 b = *(const float4*)(row + tid * 8 + 4);
  float v[8] = {a.x, a.y, a.z, a.w, b.x, b.y, b.z, b.w};
  float am = 0.f;
#pragma unroll
  for (int j = 0; j < 8; ++j) am = fmaxf(am, fabsf(v[j]));
  am = fmaxf(am, __shfl_xor(am, 32)); am = fmaxf(am, __shfl_xor(am, 16));
  am = fmaxf(am, __shfl_xor(am, 8));  am = fmaxf(am, __shfl_xor(am, 4));
  am = fmaxf(am, __shfl_xor(am, 2));  am = fmaxf(am, __shfl_xor(am, 1));
  __shared__ float red[4];
  int lane = tid & 63, wid = tid >> 6;
  if (lane == 0) red[wid] = am;
  __syncthreads();
  am = fmaxf(fmaxf(red[0], red[1]), fmaxf(red[2], red[3]));
  float a_ = fmaxf(am, 1e-5f);
  float sx = 127.0f / a_;
  char8 r;
#pragma unroll
  for (int j = 0; j < 8; ++j) {
    float q = rintf(v[j] * sx);
    q = fminf(fmaxf(q, -128.f), 127.f);
    r[j] = (char)(int)q;
  }
  *(char8*)(outq + (size_t)tok * E + tid * 8) = r;
  if (tid == 0) tokscale[tok] = a_ / 127.0f;
}

// ---------------- int8 exact GEMM, double-buffered prefetch ----------------
// mode 0: C f32 [row][col] ; mode 1: hi/lo bf16 flat ; mode 3: hi/lo bf16 vT [b][col][s]
__global__ __launch_bounds__(256) void gemm_i8_kernel(const char* A, const char* B,
                                                      float* C, unsigned short* Ohi, unsigned short* Olo,
                                                      const float* tokscale, const double* wsum,
                                                      int mode, float extra) {
  __shared__ __align__(16) char As[2][128 * 128];
  __shared__ __align__(16) char Bs[2][128 * 128];
  int tid = threadIdx.x;
  int lane = tid & 63, wid = tid >> 6;
  int bid = (int)blockIdx.x;
  int sbid = (bid & 7) * 64 + (bid >> 3);          // XCD swizzle (512 % 8 == 0)
  int bm = sbid >> 4, bn = sbid & 15;
  int wr = wid >> 1, wc = wid & 1;
  i32x4 acc[4][4];
#pragma unroll
  for (int i = 0; i < 4; ++i)
#pragma unroll
    for (int j = 0; j < 4; ++j) acc[i][j] = (i32x4){0, 0, 0, 0};

  auto stage = [&](int buf, int ks) {
#pragma unroll
    for (int i = 0; i < 4; ++i) {
      int c = i * 256 + tid;
      int row = c >> 3, col = (c & 7) * 16;
      GLDS16(A + (size_t)(bm * 128 + row) * E + ks * 128 + col, &As[buf][(i * 256 + wid * 64) * 16]);
      GLDS16(B + (size_t)(bn * 128 + row) * E + ks * 128 + col, &Bs[buf][(i * 256 + wid * 64) * 16]);
    }
  };

  stage(0, 0);
  for (int ks = 0; ks < 16; ++ks) {
    int buf = ks & 1;
    __syncthreads();
    if (ks + 1 < 16) stage(buf ^ 1, ks + 1);
#pragma unroll
    for (int kc = 0; kc < 2; ++kc) {
      i32x4 af[4], bf_[4];
#pragma unroll
      for (int mi = 0; mi < 4; ++mi)
        af[mi] = *(const i32x4*)&As[buf][(wr * 64 + mi * 16 + (lane & 15)) * 128 + kc * 64 + (lane >> 4) * 16];
#pragma unroll
      for (int nj = 0; nj < 4; ++nj)
        bf_[nj] = *(const i32x4*)&Bs[buf][(wc * 64 + nj * 16 + (lane & 15)) * 128 + kc * 64 + (lane >> 4) * 16];
#pragma unroll
      for (int mi = 0; mi < 4; ++mi)
#pragma unroll
        for (int nj = 0; nj < 4; ++nj)
          acc[mi][nj] = __builtin_amdgcn_mfma_i32_16x16x64_i8(af[mi], bf_[nj], acc[mi][nj], 0, 0, 0);
    }
  }

  float wsc = fmaxf((float)(wsum[0] * (1.0 / 4194304.0)), 1e-5f);
  int rbase = bm * 128 + wr * 64 + (lane >> 4) * 4;
  int cbase = bn * 128 + wc * 64 + (lane & 15);
  if (mode == 0) {
#pragma unroll
    for (int mi = 0; mi < 4; ++mi)
#pragma unroll
      for (int nj = 0; nj < 4; ++nj) {
        int row0 = rbase + mi * 16;
        int col = cbase + nj * 16;
#pragma unroll
        for (int r = 0; r < 4; ++r) {
          int row = row0 + r;
          C[(size_t)row * E + col] = (float)acc[mi][nj][r] * tokscale[row] * wsc * extra;
        }
      }
  } else if (mode == 1) {
#pragma unroll
    for (int mi = 0; mi < 4; ++mi)
#pragma unroll
      for (int nj = 0; nj < 4; ++nj) {
        int row0 = rbase + mi * 16;
        int col = cbase + nj * 16;
#pragma unroll
        for (int r = 0; r < 4; ++r) {
          int row = row0 + r;
          float v = (float)acc[mi][nj][r] * tokscale[row] * wsc * extra;
          unsigned short hb = f2bf(v);
          Ohi[(size_t)row * E + col] = hb;
          Olo[(size_t)row * E + col] = f2bf(v - bf2f(hb));
        }
      }
  } else {  // mode 3: transposed vT [b][col][s]
#pragma unroll
    for (int mi = 0; mi < 4; ++mi)
#pragma unroll
      for (int nj = 0; nj < 4; ++nj) {
        int row0 = rbase + mi * 16;
        int col = cbase + nj * 16;
        ushort4_t h4, l4;
#pragma unroll
        for (int r = 0; r < 4; ++r) {
          float v = (float)acc[mi][nj][r] * tokscale[row0 + r] * wsc * extra;
          h4[r] = f2bf(v);
          l4[r] = f2bf(v - bf2f(h4[r]));
        }
        size_t off = ((size_t)((row0 >> 11) * 2048 + col)) * S + (row0 & 2047);
        *(ushort4_t*)(Ohi + off) = h4;
        *(ushort4_t*)(Olo + off) = l4;
      }
  }
}

// ---------------- flash attention v3: swapped-operand 32x32 MFMA, lane-local softmax ----
// qhi/qlo: [4096][2048] bf16, q pre-scaled by log2(e)/sqrt(D).
// khi/klo: [4096][2048] bf16 ; vthi/vtlo: [b(2)][2048 d][2048 s] bf16 ; ao: [4096][2048] f32
// Block: 4 waves; wave owns 32 q rows (q = lane&31). KVBLK=32, hi/lo K/V in sliced LDS.
__global__ __launch_bounds__(256) void attn3_kernel(
    const unsigned short* __restrict__ qhi, const unsigned short* __restrict__ qlo,
    const unsigned short* __restrict__ khi, const unsigned short* __restrict__ klo,
    const unsigned short* __restrict__ vthi, const unsigned short* __restrict__ vtlo,
    float* __restrict__ ao) {
  // per buffer 32KB: Kh | Kl | Vh | Vl (8KB each), fragment-sliced, conflict-free
  __shared__ __align__(16) char L[2][32768];

  int tid = threadIdx.x, lane = tid & 63, wid = tid >> 6;
  int q5 = lane & 31, hi = lane >> 5;
  int id = blockIdx.x;
  int p = (id & 255) >> 5, bh = id & 31;
  int qb = (id >> 8) ? (15 - p) : p;                 // pair (p, 15-p) per CU for balance
  int b = bh >> 4, h = bh & 15;
  size_t hoff = (size_t)h * 128;
  size_t vrow = (size_t)b * 2048 + h * 128;
  int qs = qb * 128;
  int nt = 4 * qb + 4;
  int myq = qs + wid * 32 + q5;                      // this lane's q row
  size_t qtok = (size_t)(b * S + myq);

  // Q B-fragments: lane holds Q[q=myq][d = kc*16 + hi*8 + j]
  short8 qfh[8], qfl[8];
#pragma unroll
  for (int kc = 0; kc < 8; ++kc) {
    size_t off = qtok * E + hoff + kc * 16 + hi * 8;
    qfh[kc] = *(const short8*)(qhi + off);
    qfl[kc] = *(const short8*)(qlo + off);
  }

  f32x16 o2[4];
#pragma unroll
  for (int dt = 0; dt < 4; ++dt)
#pragma unroll
    for (int r = 0; r < 16; ++r) o2[dt][r] = 0.f;
  float m_ = -__builtin_inff();
  float lp = 0.f;

  // staging: wave w owns section w: 0=Kh 1=Kl 2=Vh 3=Vl (8KB = 8 GLDS16 each)
  const unsigned short* bsrc = (wid == 0) ? khi : (wid == 1) ? klo : (wid == 2) ? vthi : vtlo;
  auto stage = [&](int buf, int kt) {
    char* dst = &L[buf][wid * 8192];
    int tok0 = b * S + kt * 32;
    if (wid < 2) {
#pragma unroll
      for (int i = 0; i < 8; ++i) {
        int c = i * 64 + lane;                       // chunk: slice = c>>5 (kc*2+hi2), kv = c&31
        int slice = c >> 5, kv = c & 31;
        const unsigned short* src = bsrc + (size_t)(tok0 + kv) * E + hoff
                                    + (slice >> 1) * 16 + (slice & 1) * 8;
        GLDS16(src, dst + i * 1024);
      }
    } else {
#pragma unroll
      for (int i = 0; i < 8; ++i) {
        int c = i * 64 + lane;                       // chunk: sl = c>>7 (ks*2+hi2), d = c&127
        int sl = c >> 7, d = c & 127;
        const unsigned short* src = bsrc + (vrow + d) * (size_t)S + kt * 32
                                    + (sl >> 1) * 16 + (sl & 1) * 8;
        GLDS16(src, dst + i * 1024);
      }
    }
  };

  stage(0, 0);
  for (int kt = 0; kt < nt; ++kt) {
    int buf = kt & 1;
    __syncthreads();
    if (kt + 1 < nt) stage(buf ^ 1, kt + 1);
    if (kt * 32 > qs + wid * 32 + 31) continue;      // tile fully masked for this wave

    const char* KB = &L[buf][0];
    const char* VB = &L[buf][16384];

    // ---- S^T = K . Q^T (hi*hi + hi*lo + lo*hi), 32x32x16 ----
    f32x16 s;
#pragma unroll
    for (int r = 0; r < 16; ++r) s[r] = 0.f;
    __builtin_amdgcn_s_setprio(1);
#pragma unroll
    for (int kc = 0; kc < 8; ++kc) {
      short8 kh = *(const short8*)(KB + (kc * 2 + hi) * 512 + q5 * 16);
      short8 kl = *(const short8*)(KB + 8192 + (kc * 2 + hi) * 512 + q5 * 16);
      s = __builtin_amdgcn_mfma_f32_32x32x16_bf16(kh, qfh[kc], s, 0, 0, 0);
      s = __builtin_amdgcn_mfma_f32_32x32x16_bf16(kh, qfl[kc], s, 0, 0, 0);
      s = __builtin_amdgcn_mfma_f32_32x32x16_bf16(kl, qfh[kc], s, 0, 0, 0);
    }
    __builtin_amdgcn_s_setprio(0);

    // ---- causal mask: row kv = kt*32 + (r&3)+8*(r>>2)+4*hi, col q = myq ----
    if (kt * 32 + 31 > qs + wid * 32) {
#pragma unroll
      for (int r = 0; r < 16; ++r) {
        int kv = kt * 32 + (r & 3) + 8 * (r >> 2) + 4 * hi;
        if (kv > myq) s[r] = -1e30f;
      }
    }

    // ---- lane-local row max (+ partner half via shfl 32) ----
    float rm = s[0];
#pragma unroll
    for (int r = 1; r < 16; ++r) rm = fmaxf(rm, s[r]);
    rm = fmaxf(rm, __shfl_xor(rm, 32));
    float need = rm - m_;
    bool fastp = (__ballot(need <= 11.0f) == ~0ULL);   // defer-max, exp2 units
    if (!fastp) {
      float mn = fmaxf(m_, rm);
      float al = __builtin_amdgcn_exp2f(m_ - mn);
      m_ = mn;
      lp *= al;
#pragma unroll
      for (int dt = 0; dt < 4; ++dt)
#pragma unroll
        for (int r = 0; r < 16; ++r) o2[dt][r] *= al;
    }

    // ---- P = exp2(S - m), per-lane partial l ----
    float pv[16];
    float ps = 0.f;
#pragma unroll
    for (int r = 0; r < 16; ++r) { pv[r] = __builtin_amdgcn_exp2f(s[r] - m_); ps += pv[r]; }
    lp += ps;

    // ---- pack P -> bf16 hi/lo word pairs; quad t covers kv = 8t + 4*hi + {0..3} ----
    unsigned ph[4][2], plo[4][2];
#pragma unroll
    for (int t = 0; t < 4; ++t) {
      unsigned short h0 = f2bf(pv[4 * t]),     h1 = f2bf(pv[4 * t + 1]);
      unsigned short h2 = f2bf(pv[4 * t + 2]), h3 = f2bf(pv[4 * t + 3]);
      ph[t][0] = (unsigned)h0 | ((unsigned)h1 << 16);
      ph[t][1] = (unsigned)h2 | ((unsigned)h3 << 16);
      unsigned short l0 = f2bf(pv[4 * t]     - bf2f(h0));
      unsigned short l1 = f2bf(pv[4 * t + 1] - bf2f(h1));
      unsigned short l2 = f2bf(pv[4 * t + 2] - bf2f(h2));
      unsigned short l3 = f2bf(pv[4 * t + 3] - bf2f(h3));
      plo[t][0] = (unsigned)l0 | ((unsigned)l1 << 16);
      plo[t][1] = (unsigned)l2 | ((unsigned)l3 << 16);
    }
    // ---- P^T B-fragments via permlane32_swap (vdst.hi32 <-> vsrc.lo32) ----
    short8 pbh[2], pbl[2];
#pragma unroll
    for (int ks = 0; ks < 2; ++ks) {
      u32x2 r0 = __builtin_amdgcn_permlane32_swap(ph[2 * ks][0], ph[2 * ks + 1][0], false, false);
      u32x2 r1 = __builtin_amdgcn_permlane32_swap(ph[2 * ks][1], ph[2 * ks + 1][1], false, false);
      i32x4 wv; wv[0] = (int)r0[0]; wv[1] = (int)r1[0]; wv[2] = (int)r0[1]; wv[3] = (int)r1[1];
      pbh[ks] = __builtin_bit_cast(short8, wv);
      u32x2 r2 = __builtin_amdgcn_permlane32_swap(plo[2 * ks][0], plo[2 * ks + 1][0], false, false);
      u32x2 r3 = __builtin_amdgcn_permlane32_swap(plo[2 * ks][1], plo[2 * ks + 1][1], false, false);
      i32x4 wl; wl[0] = (int)r2[0]; wl[1] = (int)r3[0]; wl[2] = (int)r2[1]; wl[3] = (int)r3[1];
      pbl[ks] = __builtin_bit_cast(short8, wl);
    }

    // ---- O^T += V^T . P (hi/lo split), 32x32x16 ----
    __builtin_amdgcn_s_setprio(1);
#pragma unroll
    for (int dt = 0; dt < 4; ++dt) {
#pragma unroll
      for (int ks = 0; ks < 2; ++ks) {
        short8 vh = *(const short8*)(VB + (ks * 2 + hi) * 2048 + (dt * 32 + q5) * 16);
        short8 vl = *(const short8*)(VB + 8192 + (ks * 2 + hi) * 2048 + (dt * 32 + q5) * 16);
        o2[dt] = __builtin_amdgcn_mfma_f32_32x32x16_bf16(vh, pbh[ks], o2[dt], 0, 0, 0);
        o2[dt] = __builtin_amdgcn_mfma_f32_32x32x16_bf16(vh, pbl[ks], o2[dt], 0, 0, 0);
        o2[dt] = __builtin_amdgcn_mfma_f32_32x32x16_bf16(vl, pbh[ks], o2[dt], 0, 0, 0);
      }
    }
    __builtin_amdgcn_s_setprio(0);
  }

  // ---- epilogue: l = own + partner halves; scatter O^T -> ao[q][d] ----
  float lt = lp + __shfl_xor(lp, 32);
  float linv = 1.0f / lt;
  float* aorow = ao + qtok * E + hoff;
#pragma unroll
  for (int dt = 0; dt < 4; ++dt)
#pragma unroll
    for (int r = 0; r < 16; ++r) {
      int dloc = (r & 3) + 8 * (r >> 2) + 4 * hi;
      aorow[dt * 32 + dloc] = o2[dt][r] * linv;
    }
}

// ---------------- launch ----------------
extern "C" void kernel_launch(void* const* d_in, const int* in_sizes, int n_in,
                              void* d_out, int out_size, void* d_ws, size_t ws_size,
                              hipStream_t stream) {
  (void)in_sizes; (void)n_in; (void)out_size; (void)ws_size;
  const float* x  = (const float*)d_in[0];
  const float* w0 = (const float*)d_in[1];
  const float* w1 = (const float*)d_in[2];
  const float* w2 = (const float*)d_in[3];
  const float* w3 = (const float*)d_in[4];
  float* out = (float*)d_out;
  char* ws = (char*)d_ws;

  // q pre-scale: log2(e)/sqrt(128)  (attention uses exp2)
  const float invs_l2e = 0.088388347648318447f * 1.4426950408889634f;
  size_t WQB = (size_t)E * E;                 // bytes per int8 weight matrix
  size_t TE  = (size_t)TOK * E;

  double* wsum = (double*)ws;                         // 32 B
  float* tsx   = (float*)(ws + 256);                  // 16 KB
  float* tsa   = (float*)(ws + 256 + 16384);          // 16 KB
  char* wq   = ws + 33024;                            // 4 x 4.19 MB int8
  char* xq   = wq + 4 * WQB;                          // 8.39 MB int8
  unsigned short* qhi  = (unsigned short*)(xq + TE);  // 6 x 16.78 MB bf16
  unsigned short* qlo  = qhi + TE;
  unsigned short* khi  = qlo + TE;
  unsigned short* klo  = khi + TE;
  unsigned short* vthi = klo + TE;
  unsigned short* vtlo = vthi + TE;
  float* aof = (float*)(vtlo + TE);                   // 33.55 MB
  char* aq = xq;                                      // alias: xq dead after v-GEMM

  hipMemsetAsync(ws, 0, 64, stream);
  wabs_kernel<<<dim3(64, 4), 256, 0, stream>>>(w0, w1, w2, w3, wsum);
  wquant_kernel<<<dim3(2048, 4), 256, 0, stream>>>(w0, w1, w2, w3, wq, wsum);
  actquant_kernel<<<TOK, 256, 0, stream>>>(x, xq, tsx);
  gemm_i8_kernel<<<512, 256, 0, stream>>>(xq, wq + 0 * WQB, nullptr, qhi, qlo, tsx, wsum + 0, 1, invs_l2e);
  gemm_i8_kernel<<<512, 256, 0, stream>>>(xq, wq + 1 * WQB, nullptr, khi, klo, tsx, wsum + 1, 1, 1.0f);
  gemm_i8_kernel<<<512, 256, 0, stream>>>(xq, wq + 2 * WQB, nullptr, vthi, vtlo, tsx, wsum + 2, 3, 1.0f);
  attn3_kernel<<<512, 256, 0, stream>>>(qhi, qlo, khi, klo, vthi, vtlo, aof);
  actquant_kernel<<<TOK, 256, 0, stream>>>(aof, aq, tsa);
  gemm_i8_kernel<<<512, 256, 0, stream>>>(aq, wq + 3 * WQB, out, nullptr, nullptr, tsa, wsum + 3, 0, 1.0f);
}